// Round 6
// baseline (307.302 us; speedup 1.0000x reference)
//
#include <hip/hip_runtime.h>
#include <hip/hip_bf16.h>
#include <stdint.h>

typedef __bf16 bf16x8 __attribute__((ext_vector_type(8)));
typedef __bf16 bf16x4 __attribute__((ext_vector_type(4)));
typedef float f32x4 __attribute__((ext_vector_type(4)));
typedef unsigned short ushort_t;

// Shapes: B=2, S=2048, D=1024, H=16, HD=64.  M = B*S = 4096.

__device__ inline ushort_t f2bf(float f) {
  union { float f; uint32_t u; } v; v.f = f;
  uint32_t r = (v.u + 0x7fffu + ((v.u >> 16) & 1u)) >> 16;  // RNE
  return (ushort_t)r;
}

// pack 8 fp32 (two float4) -> 8 bf16 (uint4) via v_cvt_pk_bf16_f32
__device__ inline uint4 pack8(const float4& a, const float4& b) {
  union { __hip_bfloat162 h[4]; uint4 v; } pk;
  pk.h[0] = __float22bfloat162_rn(float2{a.x, a.y});
  pk.h[1] = __float22bfloat162_rn(float2{a.z, a.w});
  pk.h[2] = __float22bfloat162_rn(float2{b.x, b.y});
  pk.h[3] = __float22bfloat162_rn(float2{b.z, b.w});
  return pk.v;
}

// ---------------- weight convert ----------------
__global__ void cvt_w(const float* __restrict__ a, const float* __restrict__ b,
                      const float* __restrict__ c, const float* __restrict__ d,
                      ushort_t* __restrict__ out) {
  const float* srcs[4] = {a, b, c, d};
  const float* s = srcs[blockIdx.y];
  ushort_t* o = out + (size_t)blockIdx.y * 1048576;
  int i = blockIdx.x * blockDim.x + threadIdx.x;
  float4 f = ((const float4*)s)[i];
  union { ushort_t u[4]; uint2 v; } r;
  r.u[0] = f2bf(f.x); r.u[1] = f2bf(f.y); r.u[2] = f2bf(f.z); r.u[3] = f2bf(f.w);
  ((uint2*)(o))[i] = r.v;
}

// ---------------- QKV projection (NT GEMM, fp32 x + bf16 W in, bf16 out) -------------
// 128x128 tile, BK=64, 4 waves (2x2), 4x4 MFMA tiles. REGISTER-PREFETCH pipeline
// (attn-proven): next tile's global loads issue right after commit and are consumed
// next iteration -> load latency overlaps the 32-MFMA window instead of sitting
// between the barriers. x is loaded fp32 and converted in-register (cvt_x fused).
// XOR chunk swizzle retained (conflicts measured 0).
// z=0: q -> [B,H,S,HD] scaled 0.125*log2e ; z=1: k ; z=2: operand-swapped V^T -> [B,H,HD,S].
__global__ __launch_bounds__(256, 3) void qkv_gemm(
    const float* __restrict__ x,
    const ushort_t* __restrict__ qwb, const ushort_t* __restrict__ kwb, const ushort_t* __restrict__ vwb,
    const float* __restrict__ qbias, const float* __restrict__ kbias, const float* __restrict__ vbias,
    ushort_t* __restrict__ qo, ushort_t* __restrict__ ko, ushort_t* __restrict__ vto)
{
  const int z = blockIdx.z;
  const float* bias = (z == 0) ? qbias : (z == 1) ? kbias : vbias;
  const ushort_t* Wsrc = (z == 0) ? qwb : (z == 1) ? kwb : vwb;
  int m0, n0;
  if (z == 2) { m0 = blockIdx.x * 128; n0 = blockIdx.y * 128; }  // m=Wv rows p, n=tok
  else        { m0 = blockIdx.y * 128; n0 = blockIdx.x * 128; }  // m=tok, n=feature

  __shared__ __align__(16) ushort_t As[128 * 64];  // 16 KB
  __shared__ __align__(16) ushort_t Bs[128 * 64];  // 16 KB
  // fp32-staged tile (x) and bf16-staged tile (W) map to As/Bs per z:
  ushort_t* XLds = (z == 2) ? Bs : As;
  ushort_t* WLds = (z == 2) ? As : Bs;
  const int xrow0 = (z == 2) ? n0 : m0;  // token rows of x
  const int wrow0 = (z == 2) ? m0 : n0;  // weight rows

  const int tid = threadIdx.x;
  const int w = tid >> 6;
  const int lane = tid & 63;
  const int ln = lane & 15;
  const int q4 = lane >> 4;
  const int wm = w & 1, wn = w >> 1;

  // per-thread staging slots: 4 chunks of 16B per tile, slot c holds global chunk
  // g=(c&7)^(row&7) of row c>>3 (XOR swizzle; read side unchanged)
  int srow[4], sg[4];
  #pragma unroll
  for (int i = 0; i < 4; i++) {
    int c = tid + i * 256;
    srow[i] = c >> 3;
    sg[i] = (c & 7) ^ (srow[i] & 7);
  }

  f32x4 acc[4][4];
  #pragma unroll
  for (int i = 0; i < 4; i++)
    #pragma unroll
    for (int j = 0; j < 4; j++) acc[i][j] = f32x4{0.f, 0.f, 0.f, 0.f};

  float4 fx[8];   // fp32 x tile: 4 chunks x 8 floats
  uint4 wreg[4];  // bf16 W tile: 4 chunks

  // prologue: load tile k0=0
  #pragma unroll
  for (int i = 0; i < 4; i++) {
    const float* xs = &x[(size_t)(xrow0 + srow[i]) * 1024 + sg[i] * 8];
    fx[2 * i] = *(const float4*)xs;
    fx[2 * i + 1] = *(const float4*)(xs + 4);
    wreg[i] = *(const uint4*)(&Wsrc[(size_t)(wrow0 + srow[i]) * 1024 + sg[i] * 8]);
  }

  for (int k0 = 0; k0 < 1024; k0 += 64) {
    __syncthreads();  // prev iter's LDS readers done
    #pragma unroll
    for (int i = 0; i < 4; i++) {
      int c = tid + i * 256;
      *(uint4*)(&XLds[c * 8]) = pack8(fx[2 * i], fx[2 * i + 1]);
      *(uint4*)(&WLds[c * 8]) = wreg[i];
    }
    __syncthreads();

    if (k0 + 64 < 1024) {  // prefetch next tile; consumed next iter
      int kn = k0 + 64;
      #pragma unroll
      for (int i = 0; i < 4; i++) {
        const float* xs = &x[(size_t)(xrow0 + srow[i]) * 1024 + kn + sg[i] * 8];
        fx[2 * i] = *(const float4*)xs;
        fx[2 * i + 1] = *(const float4*)(xs + 4);
        wreg[i] = *(const uint4*)(&Wsrc[(size_t)(wrow0 + srow[i]) * 1024 + kn + sg[i] * 8]);
      }
    }

    #pragma unroll
    for (int ks = 0; ks < 2; ks++) {
      bf16x8 af[4], bfr[4];
      #pragma unroll
      for (int t = 0; t < 4; t++) {
        int rr = wm * 64 + t * 16 + ln;
        af[t]  = *(const bf16x8*)(&As[rr * 64 + (((ks * 4 + q4) ^ (rr & 7)) * 8)]);
        int rc = wn * 64 + t * 16 + ln;
        bfr[t] = *(const bf16x8*)(&Bs[rc * 64 + (((ks * 4 + q4) ^ (rc & 7)) * 8)]);
      }
      #pragma unroll
      for (int tm = 0; tm < 4; tm++)
        #pragma unroll
        for (int tn = 0; tn < 4; tn++)
          acc[tm][tn] = __builtin_amdgcn_mfma_f32_16x16x32_bf16(af[tm], bfr[tn], acc[tm][tn], 0, 0, 0);
    }
  }

  if (z == 2) {
    #pragma unroll
    for (int tn = 0; tn < 4; tn++) {
      int col = n0 + wn * 64 + tn * 16 + ln;   // token
      int bb = col >> 11, s = col & 2047;
      size_t base = (size_t)bb * 2097152 + s;
      #pragma unroll
      for (int tm = 0; tm < 4; tm++) {
        int prow = m0 + wm * 64 + tm * 16 + q4 * 4;
        #pragma unroll
        for (int r = 0; r < 4; r++) {
          int p = prow + r;
          vto[base + (size_t)p * 2048] = f2bf(acc[tm][tn][r] + bias[p]);
        }
      }
    }
  } else {
    #pragma unroll
    for (int tn = 0; tn < 4; tn++) {
      int col = n0 + wn * 64 + tn * 16 + ln;
      float bv = bias[col];
      int h = col >> 6, hd = col & 63;
      #pragma unroll
      for (int tm = 0; tm < 4; tm++) {
        int rowb = m0 + wm * 64 + tm * 16 + q4 * 4;
        #pragma unroll
        for (int r = 0; r < 4; r++) {
          int row = rowb + r;
          int b = row >> 11, s = row & 2047;
          float val = acc[tm][tn][r] + bv;
          if (z == 0) {
            qo[((size_t)((b * 16 + h) * 2048 + s)) * 64 + hd] = f2bf(val * 0.180336884f);
          } else {
            ko[((size_t)((b * 16 + h) * 2048 + s)) * 64 + hd] = f2bf(val);
          }
        }
      }
    }
  }
}

// ---------------- Flash attention (unchanged from R5) ----------------
#define PAD 72
#define PPAD 68
__global__ __launch_bounds__(256) void attn(
    const ushort_t* __restrict__ qp, const ushort_t* __restrict__ kp,
    const ushort_t* __restrict__ vtp, ushort_t* __restrict__ op)
{
  __shared__ __align__(16) ushort_t Ks[64 * PAD];
  __shared__ __align__(16) ushort_t Vts[64 * PAD];
  __shared__ __align__(16) ushort_t Ps[8][16 * PPAD];

  const int tid = threadIdx.x;
  const int w = tid >> 6;
  const int lane = tid & 63;
  const int ln = lane & 15;
  const int q4 = lane >> 4;
  const int bh = blockIdx.y;
  const int b = bh >> 4, h = bh & 15;
  int tswz = (blockIdx.x + blockIdx.y) & 15;
  const int qt = (blockIdx.y & 16) ? (15 - tswz) : tswz;  // mirrored pairing
  const int q0 = qt * 128;
  const int nt = 2 * qt + 2;

  const int c0 = tid, c1 = tid + 256;
  const int kr0_row = c0 >> 3, kr0_col = (c0 & 7) * 8;
  const int kr1_row = c1 >> 3, kr1_col = (c1 & 7) * 8;

  bf16x8 onesf;
  {
    union { ushort_t u[8]; bf16x8 v; } t;
    #pragma unroll
    for (int j = 0; j < 8; j++) t.u[j] = 0x3F80;  // bf16 1.0
    onesf = t.v;
  }

  bf16x8 qf[2][2];
  #pragma unroll
  for (int s = 0; s < 2; s++) {
    const ushort_t* base = qp + ((size_t)bh * 2048 + q0 + w * 32 + s * 16 + ln) * 64 + q4 * 8;
    qf[s][0] = *(const bf16x8*)(base);
    qf[s][1] = *(const bf16x8*)(base + 32);
  }

  f32x4 acc_o[2][4];
  f32x4 acc_l[2];
  #pragma unroll
  for (int s = 0; s < 2; s++) {
    acc_l[s] = f32x4{0.f, 0.f, 0.f, 0.f};
    #pragma unroll
    for (int t = 0; t < 4; t++) acc_o[s][t] = f32x4{0.f, 0.f, 0.f, 0.f};
  }

  uint4 kr0, kr1, vr0, vr1;
  {
    const ushort_t* kb = kp + (size_t)bh * 2048 * 64;
    kr0 = *(const uint4*)(kb + kr0_row * 64 + kr0_col);
    kr1 = *(const uint4*)(kb + kr1_row * 64 + kr1_col);
    const ushort_t* vb = vtp + (size_t)bh * 64 * 2048;
    vr0 = *(const uint4*)(vb + (size_t)kr0_row * 2048 + kr0_col);
    vr1 = *(const uint4*)(vb + (size_t)kr1_row * 2048 + kr1_col);
  }

  for (int it = 0; it < nt; it++) {
    if (it) __syncthreads();
    *(uint4*)(&Ks [kr0_row * PAD + kr0_col]) = kr0;
    *(uint4*)(&Ks [kr1_row * PAD + kr1_col]) = kr1;
    *(uint4*)(&Vts[kr0_row * PAD + kr0_col]) = vr0;
    *(uint4*)(&Vts[kr1_row * PAD + kr1_col]) = vr1;
    __syncthreads();

    if (it + 1 < nt) {
      int kv1 = (it + 1) * 64;
      const ushort_t* kb = kp + ((size_t)bh * 2048 + kv1) * 64;
      kr0 = *(const uint4*)(kb + kr0_row * 64 + kr0_col);
      kr1 = *(const uint4*)(kb + kr1_row * 64 + kr1_col);
      const ushort_t* vb = vtp + (size_t)bh * 64 * 2048;
      vr0 = *(const uint4*)(vb + (size_t)kr0_row * 2048 + kv1 + kr0_col);
      vr1 = *(const uint4*)(vb + (size_t)kr1_row * 2048 + kv1 + kr1_col);
    }

    f32x4 sc[2][4];
    #pragma unroll
    for (int s = 0; s < 2; s++)
      #pragma unroll
      for (int t = 0; t < 4; t++) sc[s][t] = f32x4{0.f, 0.f, 0.f, 0.f};
    #pragma unroll
    for (int ks = 0; ks < 2; ks++) {
      bf16x8 kf[4];
      #pragma unroll
      for (int tn = 0; tn < 4; tn++)
        kf[tn] = *(const bf16x8*)(&Ks[(tn * 16 + ln) * PAD + ks * 32 + q4 * 8]);
      #pragma unroll
      for (int s = 0; s < 2; s++)
        #pragma unroll
        for (int tn = 0; tn < 4; tn++)
          sc[s][tn] = __builtin_amdgcn_mfma_f32_16x16x32_bf16(qf[s][ks], kf[tn], sc[s][tn], 0, 0, 0);
    }
    if (it >= 2 * qt) {
      int kv0 = it * 64;
      #pragma unroll
      for (int s = 0; s < 2; s++) {
        int qrow = q0 + w * 32 + s * 16 + q4 * 4;
        #pragma unroll
        for (int tn = 0; tn < 4; tn++) {
          int col = kv0 + tn * 16 + ln;
          #pragma unroll
          for (int r = 0; r < 4; r++)
            if (col > qrow + r) sc[s][tn][r] = -__builtin_inff();
        }
      }
    }
    #pragma unroll
    for (int s = 0; s < 2; s++)
      #pragma unroll
      for (int tn = 0; tn < 4; tn++)
        #pragma unroll
        for (int r = 0; r < 4; r++) {
          float p = __builtin_amdgcn_exp2f(sc[s][tn][r]);
          Ps[w * 2 + s][(q4 * 4 + r) * PPAD + tn * 16 + ln] = (ushort_t)(__float_as_uint(p) >> 16);
        }
    #pragma unroll
    for (int ks = 0; ks < 2; ks++) {
      bf16x8 vf[4];
      #pragma unroll
      for (int tn = 0; tn < 4; tn++)
        vf[tn] = *(const bf16x8*)(&Vts[(tn * 16 + ln) * PAD + ks * 32 + q4 * 8]);
      #pragma unroll
      for (int s = 0; s < 2; s++) {
        const ushort_t* pp = &Ps[w * 2 + s][ln * PPAD + ks * 32 + q4 * 8];  // 8B-aligned
        bf16x4 plo = *(const bf16x4*)(pp);
        bf16x4 phi = *(const bf16x4*)(pp + 4);
        bf16x8 pf = __builtin_shufflevector(plo, phi, 0, 1, 2, 3, 4, 5, 6, 7);
        acc_l[s] = __builtin_amdgcn_mfma_f32_16x16x32_bf16(pf, onesf, acc_l[s], 0, 0, 0);
        #pragma unroll
        for (int tn = 0; tn < 4; tn++)
          acc_o[s][tn] = __builtin_amdgcn_mfma_f32_16x16x32_bf16(pf, vf[tn], acc_o[s][tn], 0, 0, 0);
      }
    }
  }

  #pragma unroll
  for (int s = 0; s < 2; s++) {
    float invl[4];
    #pragma unroll
    for (int r = 0; r < 4; r++) invl[r] = __builtin_amdgcn_rcpf(acc_l[s][r]);
    #pragma unroll
    for (int tn = 0; tn < 4; tn++)
      #pragma unroll
      for (int r = 0; r < 4; r++) {
        int row = q0 + w * 32 + s * 16 + q4 * 4 + r;
        op[((size_t)b * 2048 + row) * 1024 + h * 64 + tn * 16 + ln] =
            f2bf(acc_o[s][tn][r] * invl[r]);
      }
  }
}

// ---------------- Output projection: out = O @ ow^T + ob (fp32 out) ----------------
// BM=64, BN=128, BK=64 -> grid (8,64) = 512 blocks. Register-prefetch pipeline.
__global__ __launch_bounds__(256) void out_gemm(
    const ushort_t* __restrict__ ob_in, const ushort_t* __restrict__ owb,
    const float* __restrict__ obias, float* __restrict__ out)
{
  __shared__ __align__(16) ushort_t As[64 * 64];    // 8 KB
  __shared__ __align__(16) ushort_t Bs[128 * 64];   // 16 KB

  const int tid = threadIdx.x;
  const int w = tid >> 6;
  const int lane = tid & 63;
  const int ln = lane & 15;
  const int q4 = lane >> 4;
  const int wm = w & 1, wn = w >> 1;
  const int m0 = blockIdx.y * 64;
  const int n0 = blockIdx.x * 128;

  // staging slots (XOR swizzle)
  int arow[2], ag[2], brow[4], bg[4];
  #pragma unroll
  for (int i = 0; i < 2; i++) {
    int c = tid + i * 256;
    arow[i] = c >> 3; ag[i] = (c & 7) ^ (arow[i] & 7);
  }
  #pragma unroll
  for (int i = 0; i < 4; i++) {
    int c = tid + i * 256;
    brow[i] = c >> 3; bg[i] = (c & 7) ^ (brow[i] & 7);
  }

  f32x4 acc[2][4];
  #pragma unroll
  for (int i = 0; i < 2; i++)
    #pragma unroll
    for (int j = 0; j < 4; j++) acc[i][j] = f32x4{0.f, 0.f, 0.f, 0.f};

  uint4 areg[2], breg[4];
  #pragma unroll
  for (int i = 0; i < 2; i++)
    areg[i] = *(const uint4*)(&ob_in[(size_t)(m0 + arow[i]) * 1024 + ag[i] * 8]);
  #pragma unroll
  for (int i = 0; i < 4; i++)
    breg[i] = *(const uint4*)(&owb[(size_t)(n0 + brow[i]) * 1024 + bg[i] * 8]);

  for (int k0 = 0; k0 < 1024; k0 += 64) {
    __syncthreads();
    #pragma unroll
    for (int i = 0; i < 2; i++) *(uint4*)(&As[(tid + i * 256) * 8]) = areg[i];
    #pragma unroll
    for (int i = 0; i < 4; i++) *(uint4*)(&Bs[(tid + i * 256) * 8]) = breg[i];
    __syncthreads();

    if (k0 + 64 < 1024) {
      int kn = k0 + 64;
      #pragma unroll
      for (int i = 0; i < 2; i++)
        areg[i] = *(const uint4*)(&ob_in[(size_t)(m0 + arow[i]) * 1024 + kn + ag[i] * 8]);
      #pragma unroll
      for (int i = 0; i < 4; i++)
        breg[i] = *(const uint4*)(&owb[(size_t)(n0 + brow[i]) * 1024 + kn + bg[i] * 8]);
    }

    #pragma unroll
    for (int ks = 0; ks < 2; ks++) {
      bf16x8 af[2], bfr[4];
      #pragma unroll
      for (int t = 0; t < 2; t++) {
        int rr = wm * 32 + t * 16 + ln;
        af[t] = *(const bf16x8*)(&As[rr * 64 + (((ks * 4 + q4) ^ (rr & 7)) * 8)]);
      }
      #pragma unroll
      for (int t = 0; t < 4; t++) {
        int rc = wn * 64 + t * 16 + ln;
        bfr[t] = *(const bf16x8*)(&Bs[rc * 64 + (((ks * 4 + q4) ^ (rc & 7)) * 8)]);
      }
      #pragma unroll
      for (int tm = 0; tm < 2; tm++)
        #pragma unroll
        for (int tn = 0; tn < 4; tn++)
          acc[tm][tn] = __builtin_amdgcn_mfma_f32_16x16x32_bf16(af[tm], bfr[tn], acc[tm][tn], 0, 0, 0);
    }
  }

  #pragma unroll
  for (int tn = 0; tn < 4; tn++) {
    int col = n0 + wn * 64 + tn * 16 + ln;
    float bv = obias[col];
    #pragma unroll
    for (int tm = 0; tm < 2; tm++) {
      int rowb = m0 + wm * 32 + tm * 16 + q4 * 4;
      #pragma unroll
      for (int r = 0; r < 4; r++)
        out[(size_t)(rowb + r) * 1024 + col] = acc[tm][tn][r] + bv;
    }
  }
}

extern "C" void kernel_launch(void* const* d_in, const int* in_sizes, int n_in,
                              void* d_out, int out_size, void* d_ws, size_t ws_size,
                              hipStream_t stream) {
  const float* x     = (const float*)d_in[0];
  const float* qw    = (const float*)d_in[1];
  const float* qb    = (const float*)d_in[2];
  const float* kw    = (const float*)d_in[3];
  const float* kb    = (const float*)d_in[4];
  const float* vw    = (const float*)d_in[5];
  const float* vb    = (const float*)d_in[6];
  const float* ow    = (const float*)d_in[7];
  const float* obias = (const float*)d_in[8];
  float* out = (float*)d_out;

  char* ws = (char*)d_ws;
  ushort_t* wb  = (ushort_t*)(ws + 8388608);    // qw,kw,vw,ow bf16, 2 MB each
  ushort_t* qwb = wb;
  ushort_t* kwb = wb + 1048576;
  ushort_t* vwb = wb + 2097152;
  ushort_t* owb = wb + 3145728;
  ushort_t* qo  = (ushort_t*)(ws + 16777216);   // [B,H,S,HD] bf16 = 8 MB
  ushort_t* ko  = (ushort_t*)(ws + 25165824);
  ushort_t* vto = (ushort_t*)(ws + 33554432);   // [B,H,HD,S] bf16
  ushort_t* oo  = (ushort_t*)(ws + 41943040);   // [B,S,D] bf16

  cvt_w<<<dim3(1024, 4), dim3(256), 0, stream>>>(qw, kw, vw, ow, wb);

  qkv_gemm<<<dim3(8, 32, 3), dim3(256), 0, stream>>>(x, qwb, kwb, vwb, qb, kb, vb, qo, ko, vto);
  attn<<<dim3(16, 32), dim3(256), 0, stream>>>(qo, ko, vto, oo);
  out_gemm<<<dim3(8, 64), dim3(256), 0, stream>>>(oo, owb, obias, out);
}

// Round 7
// 200.065 us; speedup vs baseline: 1.5360x; 1.5360x over previous
//
#include <hip/hip_runtime.h>
#include <hip/hip_bf16.h>
#include <stdint.h>

typedef __bf16 bf16x8 __attribute__((ext_vector_type(8)));
typedef __bf16 bf16x4 __attribute__((ext_vector_type(4)));
typedef float f32x4 __attribute__((ext_vector_type(4)));
typedef unsigned short ushort_t;

// Shapes: B=2, S=2048, D=1024, H=16, HD=64.  M = B*S = 4096.

__device__ inline ushort_t f2bf(float f) {
  union { float f; uint32_t u; } v; v.f = f;
  uint32_t r = (v.u + 0x7fffu + ((v.u >> 16) & 1u)) >> 16;  // RNE
  return (ushort_t)r;
}

// async global->LDS, 16B per lane. LDS dest must be wave-uniform base + lane*16.
__device__ inline void gll16(const void* g, void* l) {
  __builtin_amdgcn_global_load_lds((const __attribute__((address_space(1))) void*)g,
                                   (__attribute__((address_space(3))) void*)l, 16, 0, 0);
}

// ---------------- fused converts: 4 weight matrices + x, one dispatch ----------------
// grid (1024, 8): y<4 -> weights (1M elems each), y>=4 -> x quarter (y-4).
__global__ void cvt_all(const float* __restrict__ qw, const float* __restrict__ kw,
                        const float* __restrict__ vw, const float* __restrict__ ow,
                        const float* __restrict__ x,
                        ushort_t* __restrict__ wb, ushort_t* __restrict__ xb) {
  int y = blockIdx.y;
  const float* src;
  ushort_t* dst;
  if (y < 4) {
    const float* srcs[4] = {qw, kw, vw, ow};
    src = srcs[y];
    dst = wb + (size_t)y * 1048576;
  } else {
    src = x + (size_t)(y - 4) * 1048576;
    dst = xb + (size_t)(y - 4) * 1048576;
  }
  int i = blockIdx.x * blockDim.x + threadIdx.x;  // 256K float4 per y
  float4 f = ((const float4*)src)[i];
  union { ushort_t u[4]; uint2 v; } r;
  r.u[0] = f2bf(f.x); r.u[1] = f2bf(f.y); r.u[2] = f2bf(f.z); r.u[3] = f2bf(f.w);
  ((uint2*)dst)[i] = r.v;
}

// ---------------- QKV projection (NT GEMM, bf16 in, bf16 out) -------------
// R5 version (measured 50.9us, SQ_LDS_BANK_CONFLICT=0). 128x128 tile, BK=64, 4 waves
// (2x2), 4x4 MFMA tiles; gll16 staging with XOR chunk swizzle. Register-prefetch was
// tried (R6) and SPILLED (WRITE_SIZE 210MB scratch traffic) -- do not reintroduce.
// z=0: q = X@Wq^T -> [B,H,S,HD] scaled by 0.125*log2(e)
// z=1: k = X@Wk^T -> [B,H,S,HD]
// z=2: operand-swapped V^T = Wv @ X^T -> vto[B,H,HD,S] with coalesced stores.
__global__ __launch_bounds__(256) void qkv_gemm(
    const ushort_t* __restrict__ xb,
    const ushort_t* __restrict__ qwb, const ushort_t* __restrict__ kwb, const ushort_t* __restrict__ vwb,
    const float* __restrict__ qbias, const float* __restrict__ kbias, const float* __restrict__ vbias,
    ushort_t* __restrict__ qo, ushort_t* __restrict__ ko, ushort_t* __restrict__ vto)
{
  const int z = blockIdx.z;
  const float* bias = (z == 0) ? qbias : (z == 1) ? kbias : vbias;
  const ushort_t* Ap;
  const ushort_t* Bp;
  int m0, n0;
  if (z == 2) {
    Ap = vwb; Bp = xb;
    m0 = blockIdx.x * 128;   // p = h*64+hd
    n0 = blockIdx.y * 128;   // tok
  } else {
    Ap = xb; Bp = (z == 0) ? qwb : kwb;
    m0 = blockIdx.y * 128;   // tok
    n0 = blockIdx.x * 128;   // feature
  }

  __shared__ __align__(16) ushort_t As[128 * 64];  // 16 KB
  __shared__ __align__(16) ushort_t Bs[128 * 64];  // 16 KB

  const int tid = threadIdx.x;
  const int w = tid >> 6;
  const int lane = tid & 63;
  const int ln = lane & 15;
  const int q4 = lane >> 4;
  const int wm = w & 1, wn = w >> 1;

  f32x4 acc[4][4];
  #pragma unroll
  for (int i = 0; i < 4; i++)
    #pragma unroll
    for (int j = 0; j < 4; j++) acc[i][j] = f32x4{0.f, 0.f, 0.f, 0.f};

  for (int k0 = 0; k0 < 1024; k0 += 64) {
    __syncthreads();
    #pragma unroll
    for (int i = 0; i < 4; i++) {
      int c = tid + i * 256;               // 1024 chunks of 16B per tile
      int row = c >> 3;
      int cq = (c & 7) ^ (row & 7);        // XOR swizzle
      gll16(&Ap[(size_t)(m0 + row) * 1024 + k0 + cq * 8], &As[c * 8]);
      gll16(&Bp[(size_t)(n0 + row) * 1024 + k0 + cq * 8], &Bs[c * 8]);
    }
    __syncthreads();
    #pragma unroll
    for (int ks = 0; ks < 2; ks++) {
      bf16x8 af[4], bfr[4];
      #pragma unroll
      for (int t = 0; t < 4; t++) {
        int rr = wm * 64 + t * 16 + ln;
        af[t]  = *(const bf16x8*)(&As[rr * 64 + (((ks * 4 + q4) ^ (rr & 7)) * 8)]);
        int rc = wn * 64 + t * 16 + ln;
        bfr[t] = *(const bf16x8*)(&Bs[rc * 64 + (((ks * 4 + q4) ^ (rc & 7)) * 8)]);
      }
      #pragma unroll
      for (int tm = 0; tm < 4; tm++)
        #pragma unroll
        for (int tn = 0; tn < 4; tn++)
          acc[tm][tn] = __builtin_amdgcn_mfma_f32_16x16x32_bf16(af[tm], bfr[tn], acc[tm][tn], 0, 0, 0);
    }
  }

  if (z == 2) {
    #pragma unroll
    for (int tn = 0; tn < 4; tn++) {
      int col = n0 + wn * 64 + tn * 16 + ln;   // token
      int bb = col >> 11, s = col & 2047;
      size_t base = (size_t)bb * 2097152 + s;
      #pragma unroll
      for (int tm = 0; tm < 4; tm++) {
        int prow = m0 + wm * 64 + tm * 16 + q4 * 4;
        #pragma unroll
        for (int r = 0; r < 4; r++) {
          int p = prow + r;
          vto[base + (size_t)p * 2048] = f2bf(acc[tm][tn][r] + bias[p]);
        }
      }
    }
  } else {
    #pragma unroll
    for (int tn = 0; tn < 4; tn++) {
      int col = n0 + wn * 64 + tn * 16 + ln;
      float bv = bias[col];
      int h = col >> 6, hd = col & 63;
      #pragma unroll
      for (int tm = 0; tm < 4; tm++) {
        int rowb = m0 + wm * 64 + tm * 16 + q4 * 4;
        #pragma unroll
        for (int r = 0; r < 4; r++) {
          int row = rowb + r;
          int b = row >> 11, s = row & 2047;
          float val = acc[tm][tn][r] + bv;
          if (z == 0) {
            qo[((size_t)((b * 16 + h) * 2048 + s)) * 64 + hd] = f2bf(val * 0.180336884f);
          } else {
            ko[((size_t)((b * 16 + h) * 2048 + s)) * 64 + hd] = f2bf(val);
          }
        }
      }
    }
  }
}

// ---------------- Flash attention ----------------
// BQ=128 per block (4 waves x 2 strips), BKV=64. Grid (16,32), mirrored qt pairing.
// NEW vs R5: K/V LDS double-buffered -> ONE __syncthreads per KV-iter (was 2).
// Safety: writer of buf at iter it+2 is separated from readers of buf at iter it by
// the sync at it+1. LDS 54.3KB; grid-limited 2 blocks/CU unchanged. VGPRs unchanged.
// Fixed-max softmax, l via ones-MFMA, exp2-folded Q scale, Ps stride 68.
#define PAD 72
#define PPAD 68
__global__ __launch_bounds__(256) void attn(
    const ushort_t* __restrict__ qp, const ushort_t* __restrict__ kp,
    const ushort_t* __restrict__ vtp, ushort_t* __restrict__ op)
{
  __shared__ __align__(16) ushort_t Ks[2][64 * PAD];
  __shared__ __align__(16) ushort_t Vts[2][64 * PAD];
  __shared__ __align__(16) ushort_t Ps[8][16 * PPAD];

  const int tid = threadIdx.x;
  const int w = tid >> 6;
  const int lane = tid & 63;
  const int ln = lane & 15;
  const int q4 = lane >> 4;
  const int bh = blockIdx.y;
  const int b = bh >> 4, h = bh & 15;
  int tswz = (blockIdx.x + blockIdx.y) & 15;
  const int qt = (blockIdx.y & 16) ? (15 - tswz) : tswz;  // mirrored pairing
  const int q0 = qt * 128;
  const int nt = 2 * qt + 2;

  const int c0 = tid, c1 = tid + 256;
  const int kr0_row = c0 >> 3, kr0_col = (c0 & 7) * 8;
  const int kr1_row = c1 >> 3, kr1_col = (c1 & 7) * 8;

  bf16x8 onesf;
  {
    union { ushort_t u[8]; bf16x8 v; } t;
    #pragma unroll
    for (int j = 0; j < 8; j++) t.u[j] = 0x3F80;  // bf16 1.0
    onesf = t.v;
  }

  bf16x8 qf[2][2];
  #pragma unroll
  for (int s = 0; s < 2; s++) {
    const ushort_t* base = qp + ((size_t)bh * 2048 + q0 + w * 32 + s * 16 + ln) * 64 + q4 * 8;
    qf[s][0] = *(const bf16x8*)(base);
    qf[s][1] = *(const bf16x8*)(base + 32);
  }

  f32x4 acc_o[2][4];
  f32x4 acc_l[2];
  #pragma unroll
  for (int s = 0; s < 2; s++) {
    acc_l[s] = f32x4{0.f, 0.f, 0.f, 0.f};
    #pragma unroll
    for (int t = 0; t < 4; t++) acc_o[s][t] = f32x4{0.f, 0.f, 0.f, 0.f};
  }

  uint4 kr0, kr1, vr0, vr1;
  {
    const ushort_t* kb = kp + (size_t)bh * 2048 * 64;
    kr0 = *(const uint4*)(kb + kr0_row * 64 + kr0_col);
    kr1 = *(const uint4*)(kb + kr1_row * 64 + kr1_col);
    const ushort_t* vb = vtp + (size_t)bh * 64 * 2048;
    vr0 = *(const uint4*)(vb + (size_t)kr0_row * 2048 + kr0_col);
    vr1 = *(const uint4*)(vb + (size_t)kr1_row * 2048 + kr1_col);
  }

  for (int it = 0; it < nt; it++) {
    const int buf = it & 1;
    *(uint4*)(&Ks [buf][kr0_row * PAD + kr0_col]) = kr0;
    *(uint4*)(&Ks [buf][kr1_row * PAD + kr1_col]) = kr1;
    *(uint4*)(&Vts[buf][kr0_row * PAD + kr0_col]) = vr0;
    *(uint4*)(&Vts[buf][kr1_row * PAD + kr1_col]) = vr1;
    __syncthreads();  // the only barrier per iteration (dbuf makes top-sync unnecessary)

    if (it + 1 < nt) {
      int kv1 = (it + 1) * 64;
      const ushort_t* kb = kp + ((size_t)bh * 2048 + kv1) * 64;
      kr0 = *(const uint4*)(kb + kr0_row * 64 + kr0_col);
      kr1 = *(const uint4*)(kb + kr1_row * 64 + kr1_col);
      const ushort_t* vb = vtp + (size_t)bh * 64 * 2048;
      vr0 = *(const uint4*)(vb + (size_t)kr0_row * 2048 + kv1 + kr0_col);
      vr1 = *(const uint4*)(vb + (size_t)kr1_row * 2048 + kv1 + kr1_col);
    }

    f32x4 sc[2][4];
    #pragma unroll
    for (int s = 0; s < 2; s++)
      #pragma unroll
      for (int t = 0; t < 4; t++) sc[s][t] = f32x4{0.f, 0.f, 0.f, 0.f};
    #pragma unroll
    for (int ks = 0; ks < 2; ks++) {
      bf16x8 kf[4];
      #pragma unroll
      for (int tn = 0; tn < 4; tn++)
        kf[tn] = *(const bf16x8*)(&Ks[buf][(tn * 16 + ln) * PAD + ks * 32 + q4 * 8]);
      #pragma unroll
      for (int s = 0; s < 2; s++)
        #pragma unroll
        for (int tn = 0; tn < 4; tn++)
          sc[s][tn] = __builtin_amdgcn_mfma_f32_16x16x32_bf16(qf[s][ks], kf[tn], sc[s][tn], 0, 0, 0);
    }
    if (it >= 2 * qt) {
      int kv0 = it * 64;
      #pragma unroll
      for (int s = 0; s < 2; s++) {
        int qrow = q0 + w * 32 + s * 16 + q4 * 4;
        #pragma unroll
        for (int tn = 0; tn < 4; tn++) {
          int col = kv0 + tn * 16 + ln;
          #pragma unroll
          for (int r = 0; r < 4; r++)
            if (col > qrow + r) sc[s][tn][r] = -__builtin_inff();
        }
      }
    }
    #pragma unroll
    for (int s = 0; s < 2; s++)
      #pragma unroll
      for (int tn = 0; tn < 4; tn++)
        #pragma unroll
        for (int r = 0; r < 4; r++) {
          float p = __builtin_amdgcn_exp2f(sc[s][tn][r]);
          Ps[w * 2 + s][(q4 * 4 + r) * PPAD + tn * 16 + ln] = (ushort_t)(__float_as_uint(p) >> 16);
        }
    #pragma unroll
    for (int ks = 0; ks < 2; ks++) {
      bf16x8 vf[4];
      #pragma unroll
      for (int tn = 0; tn < 4; tn++)
        vf[tn] = *(const bf16x8*)(&Vts[buf][(tn * 16 + ln) * PAD + ks * 32 + q4 * 8]);
      #pragma unroll
      for (int s = 0; s < 2; s++) {
        const ushort_t* pp = &Ps[w * 2 + s][ln * PPAD + ks * 32 + q4 * 8];  // 8B-aligned
        bf16x4 plo = *(const bf16x4*)(pp);
        bf16x4 phi = *(const bf16x4*)(pp + 4);
        bf16x8 pf = __builtin_shufflevector(plo, phi, 0, 1, 2, 3, 4, 5, 6, 7);
        acc_l[s] = __builtin_amdgcn_mfma_f32_16x16x32_bf16(pf, onesf, acc_l[s], 0, 0, 0);
        #pragma unroll
        for (int tn = 0; tn < 4; tn++)
          acc_o[s][tn] = __builtin_amdgcn_mfma_f32_16x16x32_bf16(pf, vf[tn], acc_o[s][tn], 0, 0, 0);
      }
    }
  }

  #pragma unroll
  for (int s = 0; s < 2; s++) {
    float invl[4];
    #pragma unroll
    for (int r = 0; r < 4; r++) invl[r] = __builtin_amdgcn_rcpf(acc_l[s][r]);
    #pragma unroll
    for (int tn = 0; tn < 4; tn++)
      #pragma unroll
      for (int r = 0; r < 4; r++) {
        int row = q0 + w * 32 + s * 16 + q4 * 4 + r;
        op[((size_t)b * 2048 + row) * 1024 + h * 64 + tn * 16 + ln] =
            f2bf(acc_o[s][tn][r] * invl[r]);
      }
  }
}

// ---------------- Output projection: out = O @ ow^T + ob (fp32 out) ----------------
// R5 version. BM=64, BN=128, BK=64 -> grid (8,64) = 512 blocks. gll16 + XOR swizzle.
__global__ __launch_bounds__(256) void out_gemm(
    const ushort_t* __restrict__ ob_in, const ushort_t* __restrict__ owb,
    const float* __restrict__ obias, float* __restrict__ out)
{
  __shared__ __align__(16) ushort_t As[64 * 64];    // 8 KB
  __shared__ __align__(16) ushort_t Bs[128 * 64];   // 16 KB

  const int tid = threadIdx.x;
  const int w = tid >> 6;
  const int lane = tid & 63;
  const int ln = lane & 15;
  const int q4 = lane >> 4;
  const int wm = w & 1, wn = w >> 1;
  const int m0 = blockIdx.y * 64;
  const int n0 = blockIdx.x * 128;

  f32x4 acc[2][4];
  #pragma unroll
  for (int i = 0; i < 2; i++)
    #pragma unroll
    for (int j = 0; j < 4; j++) acc[i][j] = f32x4{0.f, 0.f, 0.f, 0.f};

  for (int k0 = 0; k0 < 1024; k0 += 64) {
    __syncthreads();
    #pragma unroll
    for (int i = 0; i < 2; i++) {
      int c = tid + i * 256;               // A: 512 chunks
      int row = c >> 3;
      int cq = (c & 7) ^ (row & 7);
      gll16(&ob_in[(size_t)(m0 + row) * 1024 + k0 + cq * 8], &As[c * 8]);
    }
    #pragma unroll
    for (int i = 0; i < 4; i++) {
      int c = tid + i * 256;               // B: 1024 chunks
      int row = c >> 3;
      int cq = (c & 7) ^ (row & 7);
      gll16(&owb[(size_t)(n0 + row) * 1024 + k0 + cq * 8], &Bs[c * 8]);
    }
    __syncthreads();
    #pragma unroll
    for (int ks = 0; ks < 2; ks++) {
      bf16x8 af[2], bfr[4];
      #pragma unroll
      for (int t = 0; t < 2; t++) {
        int rr = wm * 32 + t * 16 + ln;
        af[t] = *(const bf16x8*)(&As[rr * 64 + (((ks * 4 + q4) ^ (rr & 7)) * 8)]);
      }
      #pragma unroll
      for (int t = 0; t < 4; t++) {
        int rc = wn * 64 + t * 16 + ln;
        bfr[t] = *(const bf16x8*)(&Bs[rc * 64 + (((ks * 4 + q4) ^ (rc & 7)) * 8)]);
      }
      #pragma unroll
      for (int tm = 0; tm < 2; tm++)
        #pragma unroll
        for (int tn = 0; tn < 4; tn++)
          acc[tm][tn] = __builtin_amdgcn_mfma_f32_16x16x32_bf16(af[tm], bfr[tn], acc[tm][tn], 0, 0, 0);
    }
  }

  #pragma unroll
  for (int tn = 0; tn < 4; tn++) {
    int col = n0 + wn * 64 + tn * 16 + ln;
    float bv = obias[col];
    #pragma unroll
    for (int tm = 0; tm < 2; tm++) {
      int rowb = m0 + wm * 32 + tm * 16 + q4 * 4;
      #pragma unroll
      for (int r = 0; r < 4; r++)
        out[(size_t)(rowb + r) * 1024 + col] = acc[tm][tn][r] + bv;
    }
  }
}

extern "C" void kernel_launch(void* const* d_in, const int* in_sizes, int n_in,
                              void* d_out, int out_size, void* d_ws, size_t ws_size,
                              hipStream_t stream) {
  const float* x     = (const float*)d_in[0];
  const float* qw    = (const float*)d_in[1];
  const float* qb    = (const float*)d_in[2];
  const float* kw    = (const float*)d_in[3];
  const float* kb    = (const float*)d_in[4];
  const float* vw    = (const float*)d_in[5];
  const float* vb    = (const float*)d_in[6];
  const float* ow    = (const float*)d_in[7];
  const float* obias = (const float*)d_in[8];
  float* out = (float*)d_out;

  char* ws = (char*)d_ws;
  ushort_t* xb  = (ushort_t*)(ws);              // 4096x1024 bf16 = 8 MB
  ushort_t* wb  = (ushort_t*)(ws + 8388608);    // qw,kw,vw,ow bf16, 2 MB each
  ushort_t* qwb = wb;
  ushort_t* kwb = wb + 1048576;
  ushort_t* vwb = wb + 2097152;
  ushort_t* owb = wb + 3145728;
  ushort_t* qo  = (ushort_t*)(ws + 16777216);   // [B,H,S,HD] bf16 = 8 MB
  ushort_t* ko  = (ushort_t*)(ws + 25165824);
  ushort_t* vto = (ushort_t*)(ws + 33554432);   // [B,H,HD,S] bf16
  ushort_t* oo  = (ushort_t*)(ws + 41943040);   // [B,S,D] bf16

  cvt_all<<<dim3(1024, 8), dim3(256), 0, stream>>>(qw, kw, vw, ow, x, wb, xb);

  qkv_gemm<<<dim3(8, 32, 3), dim3(256), 0, stream>>>(xb, qwb, kwb, vwb, qb, kb, vb, qo, ko, vto);
  attn<<<dim3(16, 32), dim3(256), 0, stream>>>(qo, ko, vto, oo);
  out_gemm<<<dim3(8, 64), dim3(256), 0, stream>>>(oo, owb, obias, out);
}